// Round 4
// baseline (108.853 us; speedup 1.0000x reference)
//
#include <hip/hip_runtime.h>

#define NUM_NETS     100000
#define PINS_PER_NET 5
#define NUM_PINS     (NUM_NETS * PINS_PER_NET)
#define NB           512
#define BIN_H        1.953125f          /* 1000/512, exact in fp32 */
#define INV_H        0.512f             /* 512/1000 */
#define OUT_SCALE    (1.0f / 195.3125f) /* 1/(BIN_SIZE_X * 100 tracks) */

#define TILE         64                 /* bins per tile side */
#define NTX          (NB / TILE)        /* 8 */
#define NTILES      (NTX * NTX)         /* 64 */
#define STRIPE       8                  /* rows per column-scan stripe */
#define NSTRIPE      (NB / STRIPE)      /* 64 */
#define CHUNK        4096               /* records scanned per queue round */

// ---------------------------------------------------------------------------
// K1: per-net bbox -> SoA records:
//   recA[n] = {xmn, xmx, ymn, ymx}            (geometry, read by accepted only)
//   recB[n] = {wh, wv, pack(kx1,kx2), pack(ky1,ky2)}  (metadata, dense scan)
// ---------------------------------------------------------------------------
__global__ void bbox_kernel(const float* __restrict__ pin_pos,
                            const int*   __restrict__ flat_netpin,
                            const float* __restrict__ net_weights,
                            float4* __restrict__ recA,
                            float4* __restrict__ recB) {
    int n = blockIdx.x * blockDim.x + threadIdx.x;
    if (n >= NUM_NETS) return;
    float xmn = 1e30f, xmx = -1e30f, ymn = 1e30f, ymx = -1e30f;
#pragma unroll
    for (int p = 0; p < PINS_PER_NET; ++p) {
        int pi  = flat_netpin[n * PINS_PER_NET + p];
        float x = pin_pos[pi];
        float y = pin_pos[NUM_PINS + pi];
        xmn = fminf(xmn, x); xmx = fmaxf(xmx, x);
        ymn = fminf(ymn, y); ymx = fmaxf(ymx, y);
    }
    float w = net_weights[n];
    int kx1 = min(NB - 1, (int)(xmn * INV_H));
    int kx2 = min(NB - 1, (int)(xmx * INV_H));
    int ky1 = min(NB - 1, (int)(ymn * INV_H));
    int ky2 = min(NB - 1, (int)(ymx * INV_H));
    unsigned pkx = (unsigned)kx1 | ((unsigned)kx2 << 16);
    unsigned pky = (unsigned)ky1 | ((unsigned)ky2 << 16);
    recA[n] = make_float4(xmn, xmx, ymn, ymx);
    recB[n] = make_float4(w / (ymx - ymn), w / (xmx - xmn),
                          __uint_as_float(pkx), __uint_as_float(pky));
}

// ---------------------------------------------------------------------------
// K2: LDS-privatized tile accumulation with compaction queue.
// Phase 1 (dense): scan metadata, exact corner-membership test, push ids.
// Phase 2 (dense): drain queue — every lane does real stencil work.
// ---------------------------------------------------------------------------
__global__ __launch_bounds__(1024) void tile_accum_kernel(
        const float4* __restrict__ recA,
        const float4* __restrict__ recB,
        float* __restrict__ reps, int nets_per_slice) {
    __shared__ float tile[2][TILE * TILE];   /* 32 KB */
    __shared__ int   queue[CHUNK];           /* 16 KB */
    __shared__ int   qcount;
    int t   = blockIdx.x & (NTILES - 1);
    int r   = blockIdx.x >> 6;
    int tx0 = (t >> 3) * TILE;
    int ty0 = (t & 7) * TILE;
    int tid = threadIdx.x;

    float4* tf4 = (float4*)&tile[0][0];
#pragma unroll
    for (int k = tid; k < 2 * TILE * TILE / 4; k += 1024)
        tf4[k] = make_float4(0.f, 0.f, 0.f, 0.f);

    int n0 = r * nets_per_slice;
    int n1 = min(n0 + nets_per_slice, NUM_NETS);

    for (int c0 = n0; c0 < n1; c0 += CHUNK) {
        int c1 = min(c0 + CHUNK, n1);
        if (tid == 0) qcount = 0;
        __syncthreads();
        /* phase 1: dense scan of 16B metadata, exact corner-membership */
        for (int n = c0 + tid; n < c1; n += 1024) {
            float4 rb = recB[n];
            unsigned pkx = __float_as_uint(rb.z);
            unsigned pky = __float_as_uint(rb.w);
            int kx1 = (int)(pkx & 0xffffu), kx2 = (int)(pkx >> 16);
            int ky1 = (int)(pky & 0xffffu), ky2 = (int)(pky >> 16);
            /* pair {k,k+1} intersects [t0, t0+63]  <=>  k in [t0-1, t0+63] */
            bool hx = ((unsigned)(kx1 - tx0 + 1) <= TILE) |
                      ((unsigned)(kx2 - tx0 + 1) <= TILE);
            bool hy = ((unsigned)(ky1 - ty0 + 1) <= TILE) |
                      ((unsigned)(ky2 - ty0 + 1) <= TILE);
            if (hx & hy) {
                int s = atomicAdd(&qcount, 1);
                queue[s] = n;
            }
        }
        __syncthreads();
        int m = qcount;
        /* phase 2: dense stencil over accepted records */
        for (int q = tid; q < m; q += 1024) {
            int n = queue[q];
            float4 ra = recA[n];
            float4 rb = recB[n];
            unsigned pkx = __float_as_uint(rb.z);
            unsigned pky = __float_as_uint(rb.w);
            int kx1 = (int)(pkx & 0xffffu), kx2 = (int)(pkx >> 16);
            int ky1 = (int)(pky & 0xffffu), ky2 = (int)(pky >> 16);
            float xmn = ra.x, xmx = ra.y, ymn = ra.z, ymx = ra.w;
            float wh = rb.x, wv = rb.y;
            int   xi[4] = { kx1, kx1 + 1, kx2, kx2 + 1 };
            float xb[4] = { (kx1 + 1) * BIN_H - xmn,  xmn - kx1 * BIN_H,
                            xmx - (kx2 + 1) * BIN_H,  kx2 * BIN_H - xmx };
            int   yi[4] = { ky1, ky1 + 1, ky2, ky2 + 1 };
            float yv[4] = { (ky1 + 1) * BIN_H - ymn,  ymn - ky1 * BIN_H,
                            ymx - (ky2 + 1) * BIN_H,  ky2 * BIN_H - ymx };
#pragma unroll
            for (int a = 0; a < 4; ++a) {
                unsigned gx = (unsigned)(xi[a] - tx0);
                if (gx >= TILE) continue;
                float xh = xb[a] * wh, xw = xb[a] * wv;
#pragma unroll
                for (int b = 0; b < 4; ++b) {
                    unsigned gy = (unsigned)(yi[b] - ty0);
                    if (gy >= TILE) continue;
                    int idx = (int)gx * TILE + (int)gy;
                    atomicAdd(&tile[0][idx], xh * yv[b]);
                    atomicAdd(&tile[1][idx], xw * yv[b]);
                }
            }
        }
        __syncthreads();   /* queue fully drained before next chunk reuses it */
    }

    float4* dst = (float4*)(reps + (size_t)blockIdx.x * (2 * TILE * TILE));
#pragma unroll
    for (int k = tid; k < 2 * TILE * TILE / 4; k += 1024)
        dst[k] = tf4[k];
}

// ---------------------------------------------------------------------------
// K3: reduce replicas + inclusive scan along y via wave shuffles.
// Block = grid row (x). 512 threads = 8 waves.
// ---------------------------------------------------------------------------
__global__ void reduce_rowscan_kernel(const float* __restrict__ reps,
                                      float* __restrict__ Uh,
                                      float* __restrict__ Uv, int R) {
    __shared__ float swh[8], swv[8];
    int x   = blockIdx.x;
    int tid = threadIdx.x;                 /* = y */
    int lane = tid & 63, wid = tid >> 6;
    int tx = x >> 6, xr = x & (TILE - 1);
    int tl = tx * NTX + (tid >> 6 >> 0) * 0 + (tid >> 6); /* placeholder */
    /* tile index really depends on y-block: y in [0,511] -> ty = y/64 */
    tl = tx * NTX + (tid >> 6);
    int off = xr * TILE + (tid & (TILE - 1));
    float h = 0.f, v = 0.f;
    for (int r = 0; r < R; ++r) {
        const float* base = reps + (size_t)(r * NTILES + tl) * (2 * TILE * TILE);
        h += base[off];
        v += base[TILE * TILE + off];
    }
    /* wave-level inclusive scan (width 64) */
#pragma unroll
    for (int o = 1; o < 64; o <<= 1) {
        float a = __shfl_up(h, o);
        float b = __shfl_up(v, o);
        if (lane >= o) { h += a; v += b; }
    }
    if (lane == 63) { swh[wid] = h; swv[wid] = v; }
    __syncthreads();
    float oh = 0.f, ov = 0.f;
    for (int j = 0; j < wid; ++j) { oh += swh[j]; ov += swv[j]; }
    Uh[x * NB + tid] = h + oh;
    Uv[x * NB + tid] = v + ov;
}

// ---------------------------------------------------------------------------
// K4: column-scan stage 1 — per-stripe partial inclusive scans + totals.
// ---------------------------------------------------------------------------
__global__ void colscan_partial_kernel(float* __restrict__ Uh,
                                       float* __restrict__ Uv,
                                       float* __restrict__ totH,
                                       float* __restrict__ totV) {
    int s = blockIdx.x, t = threadIdx.x;   /* t = column */
    float h = 0.f, v = 0.f;
#pragma unroll
    for (int i = 0; i < STRIPE; ++i) {
        int row = s * STRIPE + i;
        h += Uh[row * NB + t];  Uh[row * NB + t] = h;
        v += Uv[row * NB + t];  Uv[row * NB + t] = v;
    }
    totH[s * NB + t] = h;
    totV[s * NB + t] = v;
}

// ---------------------------------------------------------------------------
// K5: column-scan stage 2 — exclusive stripe offsets + fused epilogue.
// ---------------------------------------------------------------------------
__global__ void colscan_finish_kernel(const float* __restrict__ Uh,
                                      const float* __restrict__ Uv,
                                      const float* __restrict__ totH,
                                      const float* __restrict__ totV,
                                      float* __restrict__ out) {
    int s = blockIdx.x, t = threadIdx.x;
    float offh = 0.f, offv = 0.f;
    for (int s2 = 0; s2 < s; ++s2) {
        offh += totH[s2 * NB + t];
        offv += totV[s2 * NB + t];
    }
#pragma unroll
    for (int i = 0; i < STRIPE; ++i) {
        int row = s * STRIPE + i;
        float h = fabsf(Uh[row * NB + t] + offh) * OUT_SCALE;
        float v = fabsf(Uv[row * NB + t] + offv) * OUT_SCALE;
        float r = fmaxf(h, v);
        out[row * NB + t] = fminf(fmaxf(r * r, 0.5f), 2.0f);
    }
}

// ---------------------------------------------------------------------------
// Fallback (tiny workspace only): global-atomic scatter + scans.
// ---------------------------------------------------------------------------
__global__ void scatter_kernel(const float* __restrict__ pin_pos,
                               const int*   __restrict__ flat_netpin,
                               const float* __restrict__ net_weights,
                               float* __restrict__ Uh,
                               float* __restrict__ Uv) {
    int n = blockIdx.x * blockDim.x + threadIdx.x;
    if (n >= NUM_NETS) return;
    float xmn = 1e30f, xmx = -1e30f, ymn = 1e30f, ymx = -1e30f;
#pragma unroll
    for (int p = 0; p < PINS_PER_NET; ++p) {
        int pi  = flat_netpin[n * PINS_PER_NET + p];
        float x = pin_pos[pi];
        float y = pin_pos[NUM_PINS + pi];
        xmn = fminf(xmn, x); xmx = fmaxf(xmx, x);
        ymn = fminf(ymn, y); ymx = fmaxf(ymx, y);
    }
    float w  = net_weights[n];
    float wh = w / (ymx - ymn), wv = w / (xmx - xmn);
    int kx1 = min(NB - 1, (int)(xmn * INV_H));
    int kx2 = min(NB - 1, (int)(xmx * INV_H));
    int ky1 = min(NB - 1, (int)(ymn * INV_H));
    int ky2 = min(NB - 1, (int)(ymx * INV_H));
    int   xi[4] = { kx1, kx1 + 1, kx2, kx2 + 1 };
    float xv[4] = { (kx1 + 1) * BIN_H - xmn,  xmn - kx1 * BIN_H,
                    xmx - (kx2 + 1) * BIN_H,  kx2 * BIN_H - xmx };
    int   yi[4] = { ky1, ky1 + 1, ky2, ky2 + 1 };
    float yv[4] = { (ky1 + 1) * BIN_H - ymn,  ymn - ky1 * BIN_H,
                    ymx - (ky2 + 1) * BIN_H,  ky2 * BIN_H - ymx };
#pragma unroll
    for (int a = 0; a < 4; ++a) {
        if (xi[a] >= NB) continue;
#pragma unroll
        for (int b = 0; b < 4; ++b) {
            if (yi[b] >= NB) continue;
            float prod = xv[a] * yv[b];
            int   idx  = xi[a] * NB + yi[b];
            atomicAdd(&Uh[idx], wh * prod);
            atomicAdd(&Uv[idx], wv * prod);
        }
    }
}

__global__ void row_scan_kernel(float* __restrict__ Uh, float* __restrict__ Uv) {
    __shared__ float sh[NB];
    __shared__ float sv[NB];
    int r = blockIdx.x;
    int t = threadIdx.x;
    sh[t] = Uh[r * NB + t];
    sv[t] = Uv[r * NB + t];
    __syncthreads();
#pragma unroll
    for (int off = 1; off < NB; off <<= 1) {
        float a = (t >= off) ? sh[t - off] : 0.0f;
        float b = (t >= off) ? sv[t - off] : 0.0f;
        __syncthreads();
        sh[t] += a; sv[t] += b;
        __syncthreads();
    }
    Uh[r * NB + t] = sh[t];
    Uv[r * NB + t] = sv[t];
}

extern "C" void kernel_launch(void* const* d_in, const int* in_sizes, int n_in,
                              void* d_out, int out_size, void* d_ws, size_t ws_size,
                              hipStream_t stream) {
    const float* pin_pos     = (const float*)d_in[0];
    const int*   flat_netpin = (const int*)d_in[2];
    const float* net_weights = (const float*)d_in[3];
    float* out = (float*)d_out;
    float* ws  = (float*)d_ws;

    /* workspace layout (floats):
       recA[N*4] | recB[N*4] | Uh | Uv | totH | totV | reps[R*...] */
    const size_t RECA  = (size_t)NUM_NETS * 4;
    const size_t GRID  = (size_t)NB * NB;
    const size_t TOT   = (size_t)NSTRIPE * NB;
    const size_t REP1  = (size_t)NTILES * 2 * TILE * TILE;   /* 2 MB */
    const size_t fixed = 2 * RECA + 2 * GRID + 2 * TOT;

    int R = 0;
    for (int cand = 8; cand >= 1; cand >>= 1) {
        if (ws_size >= (fixed + (size_t)cand * REP1) * sizeof(float)) { R = cand; break; }
    }

    if (R == 0) {
        float* Uh = ws;
        float* Uv = ws + GRID;
        float* totH = Uv + GRID;
        float* totV = totH + TOT;
        hipMemsetAsync(ws, 0, 2 * GRID * sizeof(float), stream);
        scatter_kernel<<<(NUM_NETS + 255) / 256, 256, 0, stream>>>(
            pin_pos, flat_netpin, net_weights, Uh, Uv);
        row_scan_kernel<<<NB, NB, 0, stream>>>(Uh, Uv);
        colscan_partial_kernel<<<NSTRIPE, NB, 0, stream>>>(Uh, Uv, totH, totV);
        colscan_finish_kernel<<<NSTRIPE, NB, 0, stream>>>(Uh, Uv, totH, totV, out);
        return;
    }

    float4* recA = (float4*)ws;
    float4* recB = (float4*)(ws + RECA);
    float*  Uh   = ws + 2 * RECA;
    float*  Uv   = Uh + GRID;
    float*  totH = Uv + GRID;
    float*  totV = totH + TOT;
    float*  reps = totV + TOT;
    int nets_per_slice = (NUM_NETS + R - 1) / R;

    bbox_kernel<<<(NUM_NETS + 255) / 256, 256, 0, stream>>>(
        pin_pos, flat_netpin, net_weights, recA, recB);

    tile_accum_kernel<<<NTILES * R, 1024, 0, stream>>>(recA, recB, reps,
                                                       nets_per_slice);

    reduce_rowscan_kernel<<<NB, NB, 0, stream>>>(reps, Uh, Uv, R);

    colscan_partial_kernel<<<NSTRIPE, NB, 0, stream>>>(Uh, Uv, totH, totV);

    colscan_finish_kernel<<<NSTRIPE, NB, 0, stream>>>(Uh, Uv, totH, totV, out);
}